// Round 8
// baseline (442.521 us; speedup 1.0000x reference)
//
#include <hip/hip_runtime.h>
#include <hip/hip_bf16.h>

#define H 128
#define W 128
#define CIN 128
#define COUT 64
#define HW (H*W)
#define XW 130                    // padded spatial dim (y,x in [0,129])
#define FSL (XW*XW*64)            // feats2 elems per zb slice (NHWC bf16)
#define XTD 144                   // xt padded dim

typedef __hip_bfloat16 bf16;
typedef __attribute__((ext_vector_type(8)))  short s16x8;
typedef __attribute__((ext_vector_type(16))) float f32x16;

__device__ __forceinline__ float b2f(bf16 v){ return __bfloat162float(v); }
__device__ __forceinline__ bf16  f2b(float v){ return __float2bfloat16(v); }
__device__ __forceinline__ unsigned pack2(float a, float b){
    unsigned short ua = __builtin_bit_cast(unsigned short, f2b(a));
    unsigned short ub = __builtin_bit_cast(unsigned short, f2b(b));
    return (unsigned)ua | ((unsigned)ub << 16);
}
__device__ __forceinline__ unsigned short b16u(float v){
    return __builtin_bit_cast(unsigned short, f2b(v));
}
__device__ __forceinline__ float2 up2(unsigned u){
    float lo = __builtin_bit_cast(float, u << 16);
    float hi = __builtin_bit_cast(float, u & 0xFFFF0000u);
    return make_float2(lo, hi);
}

// ---------------------------------------------------------------------------
// k_prep: [0,1024) zero xt2; [1024,1600) wbt; [1600,1672) dwb2;
//         [1672,1704) cwb2; [1704,1740) pwb
// ---------------------------------------------------------------------------
__global__ __launch_bounds__(256) void k_prep(
    const float* __restrict__ w1, const float* __restrict__ w2,
    const float* __restrict__ w3, const float* __restrict__ w4,
    const float* __restrict__ dw, const float* __restrict__ cw,
    const float* __restrict__ pw,
    uint4* __restrict__ xt4, unsigned* __restrict__ wbt,
    unsigned* __restrict__ dwb2, unsigned* __restrict__ cwb2,
    unsigned* __restrict__ pwb)
{
    int bid = blockIdx.x;
    int t = threadIdx.x;
    if (bid < 1024){
        const int n4 = (4*XTD*XTD*64)/4;        // 1327104
        for (int i = bid*256 + t; i < n4; i += 1024*256)
            xt4[i] = make_uint4(0,0,0,0);
    } else if (bid < 1600){
        int tid = (bid-1024)*256 + t;            // 147456 = 4*8*9*64*8
        int cpl = tid & 7;
        int oc  = (tid >> 3) & 63;
        int tap = (tid >> 9) % 9;
        int cg  = (tid / 4608) & 7;
        int d   = tid / 36864;
        const float* wt = (d==0)?w1:(d==1)?w2:(d==2)?w3:w4;
        int c = cg*8 + cpl;
        wbt[tid] = pack2(wt[((size_t)oc*CIN + 2*c  )*9 + tap],
                         wt[((size_t)oc*CIN + 2*c+1)*9 + tap]);
    } else if (bid < 1672){
        int i = (bid-1600)*256 + t;              // 18432: dwb2[n][oc][cp32]
        int n = i>>11, oc = (i>>5)&63, cp = i&31;
        dwb2[i] = pack2(dw[((size_t)oc*64 + 2*cp  )*9 + n],
                        dw[((size_t)oc*64 + 2*cp+1)*9 + n]);
    } else if (bid < 1704){
        int i = (bid-1672)*256 + t;              // 8192: cwb2[oc][cp128]
        int oc = i>>7, cp = i&127;
        cwb2[i] = pack2(cw[(size_t)oc*256 + 2*cp], cw[(size_t)oc*256 + 2*cp+1]);
    } else {
        int i = (bid-1704)*256 + t;              // 9216
        int cl = i & 3, oc = (i>>2)&31, hf = (i>>7)&1, cq = (i>>8)&3, tap = i>>10;
        int c = cq*16 + hf*8 + cl*2;
        unsigned v = 0u;
        if (oc < 18)
            v = pack2(pw[((size_t)oc*64 + c  )*9 + tap],
                      pw[((size_t)oc*64 + c+1)*9 + tap]);
        pwb[i] = v;
    }
}

// ---------------------------------------------------------------------------
// xprep: xt2[b][cg 8][y+8][col+8][cpl 8] u32 (interior). grid (128 y, 4 b).
// ---------------------------------------------------------------------------
__global__ __launch_bounds__(256) void k_xprep(
    const float* __restrict__ x, unsigned* __restrict__ xt)
{
    int y = blockIdx.x, b = blockIdx.y;
    int t = threadIdx.x;
    __shared__ float xsm[64*131];
    for (int ci0 = 0; ci0 < 128; ci0 += 64){
        for (int i=0;i<32;i++){
            int idx = t + 256*i;
            int col = idx & 127, ci = idx >> 7;
            xsm[ci*131 + col] = x[(((size_t)b*CIN + ci0+ci)*H + y)*W + col];
        }
        __syncthreads();
        for (int i=0;i<16;i++){
            int idx = t + 256*i;
            int cpg = idx & 31, col = idx >> 5;
            int cgg = (ci0 >> 4) + (cpg >> 3);
            int cpl = cpg & 7;
            unsigned u = pack2(xsm[(2*cpg)*131 + col], xsm[(2*cpg+1)*131 + col]);
            xt[((((size_t)b*8 + cgg)*XTD + y+8)*XTD + col+8)*8 + cpl] = u;
        }
        __syncthreads();
    }
}

// ---------------------------------------------------------------------------
// K1: dilated 3x3 conv via bf16 MFMA implicit GEMM. grid 1024 1-D, XCD swizzle.
// ---------------------------------------------------------------------------
__global__ __launch_bounds__(256,2) void k_branch_mfma(
    const unsigned* __restrict__ xt, const unsigned* __restrict__ wbt,
    const float* __restrict__ b1, const float* __restrict__ b2,
    const float* __restrict__ b3, const float* __restrict__ b4,
    bf16* __restrict__ feats2)
{
    int bid = blockIdx.x;
    int xcd = bid & 7;
    int j   = bid >> 3;
    int zb  = xcd + 8*(j & 1);
    int hp  = j >> 1;
    int d = zb >> 2, b = zb & 3;
    int dil = 2*d + 1;
    int h0 = hp*2;
    const float* bs = (d==0)?b1:(d==1)?b2:(d==2)?b3:b4;
    const float scale = (float)dil;

    __shared__ unsigned smem[10368 + 6912];
    unsigned* As = smem;
    unsigned* Bs = smem + 10368;
    const unsigned short* As16 = (const unsigned short*)As;
    const unsigned short* Bs16 = (const unsigned short*)Bs;

    int t = threadIdx.x;
    int lane = t & 63;
    int w = t >> 6;
    int l31 = lane & 31;
    int half = lane >> 5;

    bf16* fb = feats2 + (size_t)zb*FSL;
    if (t < 32){
        int yy = h0 + 1 + (t>>4);
        int side = (t>>3)&1;
        int q = t & 7;
        uint4 z = make_uint4(0,0,0,0);
        *(uint4*)((unsigned short*)fb + ((size_t)yy*XW + side*129)*64 + q*8) = z;
    }
    if (hp == 0){
        uint4 z = make_uint4(0,0,0,0);
        for (int i=t; i<2080; i+=256){
            int row = i / 1040;
            int r = i % 1040;
            int xx = r >> 3, q = r & 7;
            *(uint4*)((unsigned short*)fb + ((size_t)(row*129)*XW + xx)*64 + q*8) = z;
        }
    }

    f32x16 acc[2][2];
    #pragma unroll
    for (int i=0;i<2;i++)
      #pragma unroll
      for (int jj=0;jj<2;jj++)
        #pragma unroll
        for (int e=0;e<16;e++) acc[i][jj][e] = 0.f;

    const unsigned* xtb_b = xt + (size_t)b*8*XTD*XTD*8;
    int r = w >> 1;
    int pxb = (w & 1) * 64;

    for (int cg=0; cg<8; cg++){
        const unsigned* xs_cg = xtb_b + (size_t)cg*XTD*XTD*8;
        #pragma unroll
        for (int i=0;i<7;i++){
            int idx4 = t + 256*i;
            if (idx4 < 1728){
                int cp4 = idx4 & 1;
                int s   = (idx4 >> 1) % 144;
                int row6= idx4 / 288;
                int ky = row6 >> 1, rr = row6 & 1;
                int yy = h0 + rr + (ky-1)*dil + 8;
                uint4 v = *(const uint4*)(xs_cg + ((size_t)yy*XTD + (s + 8 - dil))*8 + cp4*4);
                *(uint4*)&As[(row6*144 + s)*12 + cp4*4] = v;
            }
        }
        const unsigned* wb_cg = wbt + ((size_t)d*8 + cg)*4608;
        #pragma unroll
        for (int i=0;i<5;i++){
            int idx4 = t + 256*i;
            if (idx4 < 1152){
                int cp4 = idx4 & 1;
                int oc  = (idx4 >> 1) & 63;
                int tap = idx4 >> 7;
                uint4 v = *(const uint4*)(wb_cg + ((size_t)tap*64 + oc)*8 + cp4*4);
                *(uint4*)&Bs[(tap*64 + oc)*12 + cp4*4] = v;
            }
        }
        __syncthreads();
        #pragma unroll
        for (int tap=0; tap<9; tap++){
            int ky = tap/3, kx = tap%3;
            int rowb = (ky*2 + r)*144;
            s16x8 a0 = *(const s16x8*)(As16 + (rowb + pxb      + l31 + kx*dil)*24 + half*8);
            s16x8 a1 = *(const s16x8*)(As16 + (rowb + pxb + 32 + l31 + kx*dil)*24 + half*8);
            s16x8 bb0 = *(const s16x8*)(Bs16 + (tap*64      + l31)*24 + half*8);
            s16x8 bb1 = *(const s16x8*)(Bs16 + (tap*64 + 32 + l31)*24 + half*8);
            acc[0][0] = __builtin_amdgcn_mfma_f32_32x32x16_bf16(a0, bb0, acc[0][0], 0,0,0);
            acc[0][1] = __builtin_amdgcn_mfma_f32_32x32x16_bf16(a0, bb1, acc[0][1], 0,0,0);
            acc[1][0] = __builtin_amdgcn_mfma_f32_32x32x16_bf16(a1, bb0, acc[1][0], 0,0,0);
            acc[1][1] = __builtin_amdgcn_mfma_f32_32x32x16_bf16(a1, bb1, acc[1][1], 0,0,0);
        }
        __syncthreads();
    }

    unsigned short* ep = (unsigned short*)smem;
    float bias0 = bs[l31], bias1 = bs[32 + l31];
    #pragma unroll
    for (int i=0;i<2;i++){
      #pragma unroll
      for (int jj=0;jj<2;jj++){
        int oc = jj*32 + l31;
        float bj = jj ? bias1 : bias0;
        #pragma unroll
        for (int rg=0; rg<4; rg++){
            int m0 = 64*w + 32*i + 8*rg + 4*half;
            #pragma unroll
            for (int e=0;e<4;e++)
                ep[(m0+e)*64 + oc] = b16u((acc[i][jj][4*rg+e] + bj)*scale);
        }
      }
    }
    __syncthreads();
    {
        int row = t >> 7, pxm = t & 127;
        unsigned short* drow = (unsigned short*)fb + ((size_t)(h0+1+row)*XW + pxm + 1)*64;
        const unsigned short* srow = ep + t*64;
        #pragma unroll
        for (int q=0;q<8;q++)
            *(uint4*)(drow + q*8) = *(const uint4*)(srow + q*8);
    }
}

// ---------------------------------------------------------------------------
// K2: 3x3 conv 64 -> 18 (offsets) via bf16 MFMA, XCD swizzle.
// ---------------------------------------------------------------------------
__global__ __launch_bounds__(256,2) void k_offset_mfma(
    const bf16* __restrict__ feats2,
    const unsigned* __restrict__ pwb,   // [tap][cq][hf][oc32][cl4] u32
    const float* __restrict__ pb,
    bf16* __restrict__ offs)
{
    int bid = blockIdx.x;
    int xcd  = bid & 7;
    int h    = (bid >> 3) & 127;
    int pass = bid >> 10;
    int zb   = xcd + 8*pass;

    int t = threadIdx.x;
    int lane = t & 63, w = t >> 6;
    int l31 = lane & 31, half = lane >> 5;

    __shared__ unsigned short xs[3*132*68];   // 53.9 KB

    const unsigned short* fin = (const unsigned short*)(feats2 + (size_t)zb*FSL);
    for (int i=t; i<3120; i+=256){
        int row = i / 1040;
        int r   = i % 1040;
        int col = r >> 3, q = r & 7;
        uint4 v = *(const uint4*)(fin + ((size_t)(h+row)*XW + col)*64 + q*8);
        *(uint4*)&xs[(row*132 + col)*68 + q*8] = v;
    }
    __syncthreads();

    f32x16 acc;
    #pragma unroll
    for (int e=0;e<16;e++) acc[e] = 0.f;

    int pxw = 32*w + l31;
    #pragma unroll
    for (int tap=0; tap<9; tap++){
        int ky = tap/3, kx = tap%3;
        const unsigned short* arow = &xs[(ky*132 + pxw + kx)*68 + half*8];
        const unsigned* brow = pwb + (((size_t)tap*4)*2 + half)*128 + l31*4;
        #pragma unroll
        for (int cq=0; cq<4; cq++){
            s16x8 a  = *(const s16x8*)(arow + cq*16);
            s16x8 b0 = *(const s16x8*)(brow + cq*256);
            acc = __builtin_amdgcn_mfma_f32_32x32x16_bf16(a, b0, acc, 0,0,0);
        }
    }
    __syncthreads();

    unsigned short* ep = (unsigned short*)xs;   // [oc 18][132 pad]
    if (l31 < 18){
        float bias = pb[l31];
        #pragma unroll
        for (int rg=0; rg<4; rg++){
            int m0 = 32*w + 4*half + 8*rg;
            #pragma unroll
            for (int e=0;e<4;e++)
                ep[l31*132 + m0+e] = b16u(acc[4*rg+e] + bias);
        }
    }
    __syncthreads();
    unsigned short* obase = (unsigned short*)(offs + (size_t)zb*18*HW) ;
    for (int i=t; i<288; i+=256){
        int oc = i >> 4, sg = i & 15;
        *(uint4*)(obase + (size_t)oc*HW + h*W + sg*8) = *(const uint4*)(ep + oc*132 + sg*8);
    }
}

// ---------------------------------------------------------------------------
// K3a: deform sampling + dw einsum via bf16 MFMA — REGISTER-DIRECT A frags.
// grid 2048 1-D, XCD swizzle. Each lane samples its OWN MFMA A fragment:
// pixel m = 32w+l31, channels sub*16 + half*8. B frags straight from global
// dwb2 (L1-resident). ZERO barriers in the K-loop; LDS only for epilogue.
// ---------------------------------------------------------------------------
__global__ __launch_bounds__(256,4) void k_deform_mfma(
    const bf16* __restrict__ feats2,
    const bf16* __restrict__ offs,
    const unsigned* __restrict__ dwb2,  // [n][oc][cp32] u32
    const float* __restrict__ db,
    bf16* __restrict__ dout2)
{
    int bid = blockIdx.x;
    int xcd  = bid & 7;
    int h    = (bid >> 3) & 127;
    int pass = bid >> 10;
    int zb   = xcd + 8*pass;

    int t = threadIdx.x;
    int lane = t & 63, w = t >> 6;
    int l31 = lane & 31, half = lane >> 5;
    int m = 32*w + l31;                       // this lane's pixel

    __shared__ unsigned short ep[128*64];     // 16 KB, epilogue only

    const bf16* obase = offs + (size_t)zb*18*HW + h*W;
    const unsigned short* fbase = (const unsigned short*)(feats2 + (size_t)zb*FSL);

    f32x16 acc0, acc1;
    #pragma unroll
    for (int e=0;e<16;e++){ acc0[e]=0.f; acc1[e]=0.f; }

    for (int n=0; n<9; n++){
        float offy = b2f(obase[n*HW + m]);
        float offx = b2f(obase[(n+9)*HW + m]);
        float py  = (float)(h + n/3) + offy;
        float pxf = (float)(m + n%3) + offx;
        float fy = floorf(py), fx = floorf(pxf);
        float lty = fminf(fmaxf(fy,     0.f),129.f);
        float ltx = fminf(fmaxf(fx,     0.f),129.f);
        float rby = fminf(fmaxf(fy+1.f, 0.f),129.f);
        float rbx = fminf(fmaxf(fx+1.f, 0.f),129.f);
        float pyc = fminf(fmaxf(py,     0.f),129.f);
        float pxc = fminf(fmaxf(pxf,    0.f),129.f);
        float ay = 1.f + (lty-pyc), by = 1.f - (rby-pyc);
        float ax = 1.f + (ltx-pxc), bx = 1.f - (rbx-pxc);
        float glt = ay*ax, glb = ay*bx, grt = by*ax, grb = by*bx;
        int base = ((int)lty*XW + (int)ltx)*64;
        int dxo  = ((int)rbx - (int)ltx)*64;
        int dyo  = ((int)rby - (int)lty)*XW*64;

        const unsigned short* fpx = fbase + base + half*8;
        const unsigned* dn = dwb2 + n*2048 + l31*32 + half*4;
        #pragma unroll
        for (int sub=0; sub<4; sub++){
            const unsigned short* fc = fpx + sub*16;
            unsigned LT[4], LB[4], RT[4], RB[4];
            *(uint4*)LT = *(const uint4*)(fc);
            *(uint4*)LB = *(const uint4*)(fc+dxo);
            *(uint4*)RT = *(const uint4*)(fc+dyo);
            *(uint4*)RB = *(const uint4*)(fc+dyo+dxo);
            unsigned pk[4];
            #pragma unroll
            for (int jq=0;jq<4;jq++){
                float2 a = up2(LT[jq]), bq = up2(LB[jq]);
                float2 c = up2(RT[jq]), dq = up2(RB[jq]);
                float slo = glt*a.x + glb*bq.x + grt*c.x + grb*dq.x;
                float shi = glt*a.y + glb*bq.y + grt*c.y + grb*dq.y;
                pk[jq] = pack2(slo, shi);
            }
            uint4 av; av.x=pk[0]; av.y=pk[1]; av.z=pk[2]; av.w=pk[3];
            s16x8 a = __builtin_bit_cast(s16x8, av);
            s16x8 b0 = *(const s16x8*)(dn + sub*8);
            s16x8 b1 = *(const s16x8*)(dn + 1024 + sub*8);
            acc0 = __builtin_amdgcn_mfma_f32_32x32x16_bf16(a, b0, acc0, 0,0,0);
            acc1 = __builtin_amdgcn_mfma_f32_32x32x16_bf16(a, b1, acc1, 0,0,0);
        }
    }

    // epilogue: +db, ep[px][oc] u16 == dout2 row layout, straight copy out
    #pragma unroll
    for (int nt=0; nt<2; nt++){
        int oc = nt*32 + l31;
        float bias = db[oc];
        const f32x16& A = nt ? acc1 : acc0;
        #pragma unroll
        for (int rg=0; rg<4; rg++){
            int m0 = 32*w + 4*half + 8*rg;
            #pragma unroll
            for (int e=0;e<4;e++)
                ep[(m0+e)*64 + oc] = b16u(A[4*rg+e] + bias);
        }
    }
    __syncthreads();
    uint4* dst = (uint4*)((unsigned short*)dout2 + ((size_t)zb*128 + h)*(128*64));
    #pragma unroll
    for (int i=0;i<4;i++)
        dst[t + 256*i] = ((const uint4*)ep)[t + 256*i];
}

// ---------------------------------------------------------------------------
// K3b: 1x1 conv 256 -> 64 + cb + ReLU via bf16 MFMA. grid (128 h, 4 b).
// ---------------------------------------------------------------------------
__global__ __launch_bounds__(256,2) void k_combine_mfma(
    const bf16* __restrict__ dout2,
    const unsigned* __restrict__ cwb2,  // [oc][cp128] u32
    const float* __restrict__ cb,
    float* __restrict__ out)
{
    int h = blockIdx.x, b = blockIdx.y;
    int t = threadIdx.x;
    int px = t & 127, hf = t >> 7;
    int lane = t & 63, w = t >> 6, l31 = lane & 31, half = lane >> 5;

    __shared__ unsigned Bsu[64*132];
    __shared__ unsigned Asu2[1024];

    for (int i=t; i<8192; i+=256){
        int oc = i>>7, cp = i&127;
        Bsu[oc*132 + cp] = cwb2[i];
    }
    f32x16 acc0, acc1;
    #pragma unroll
    for (int e=0;e<16;e++){ acc0[e]=0.f; acc1[e]=0.f; }

    const unsigned short* dbase0 = (const unsigned short*)dout2;
    size_t rowsel = ((size_t)b*128 + h)*128 + px;
    uint4 v = *(const uint4*)(dbase0 + rowsel*64 + hf*8);
    for (int kc=0; kc<16; kc++){
        *(uint4*)&Asu2[(hf*128+px)*4] = v;
        __syncthreads();
        if (kc < 15){
            int kn = kc+1;
            int d = kn>>2, c16 = kn&3;
            v = *(const uint4*)(dbase0 + ((size_t)d*4*128*128*64 + rowsel*64) + c16*16 + hf*8);
        }
        const unsigned short* As16 = (const unsigned short*)Asu2;
        const unsigned short* Bs16 = (const unsigned short*)Bsu;
        s16x8 a  = *(const s16x8*)(As16 + (half*128 + 32*w + l31)*8);
        s16x8 b0 = *(const s16x8*)(Bs16 + (l31*132 + kc*8 + half*4)*2);
        s16x8 b1 = *(const s16x8*)(Bs16 + ((32+l31)*132 + kc*8 + half*4)*2);
        acc0 = __builtin_amdgcn_mfma_f32_32x32x16_bf16(a, b0, acc0, 0,0,0);
        acc1 = __builtin_amdgcn_mfma_f32_32x32x16_bf16(a, b1, acc1, 0,0,0);
        __syncthreads();
    }
    float* ep = (float*)Bsu;
    #pragma unroll
    for (int nt=0; nt<2; nt++){
        int oc = nt*32 + l31;
        float bias = cb[oc];
        const f32x16& A = nt ? acc1 : acc0;
        #pragma unroll
        for (int rg=0; rg<4; rg++){
            int m0 = 32*w + 4*half + 8*rg;
            #pragma unroll
            for (int e=0;e<4;e++)
                ep[oc*132 + m0+e] = fmaxf(A[4*rg+e] + bias, 0.f);
        }
    }
    __syncthreads();
    for (int i=t; i<2048; i+=256){
        int oc = i>>5, sg = i&31;
        *(uint4*)&out[(((size_t)b*64+oc)*128 + h)*128 + sg*4] = *(const uint4*)&ep[oc*132 + sg*4];
    }
}

extern "C" void kernel_launch(void* const* d_in, const int* in_sizes, int n_in,
                              void* d_out, int out_size, void* d_ws, size_t ws_size,
                              hipStream_t stream) {
    const float* x  = (const float*)d_in[0];
    const float* w1 = (const float*)d_in[1];
    const float* b1 = (const float*)d_in[2];
    const float* w2 = (const float*)d_in[3];
    const float* b2 = (const float*)d_in[4];
    const float* w3 = (const float*)d_in[5];
    const float* b3 = (const float*)d_in[6];
    const float* w4 = (const float*)d_in[7];
    const float* b4 = (const float*)d_in[8];
    const float* pw = (const float*)d_in[9];
    const float* pb = (const float*)d_in[10];
    const float* dw = (const float*)d_in[11];
    const float* db = (const float*)d_in[12];
    const float* cw = (const float*)d_in[13];
    const float* cb = (const float*)d_in[14];
    float* out = (float*)d_out;

    bf16* feats2 = (bf16*)d_ws;                             // 34.6 MB
    bf16* offs   = feats2 + (size_t)16*FSL;                 // 9.4 MB
    bf16* region2 = offs + (size_t)16*18*HW;
    bf16* dout2  = region2;                                 // 33.55 MB
    unsigned* xt  = (unsigned*)region2;                     // 21.2 MB (dead before dout2)
    unsigned* wbt = xt + (size_t)4*8*XTD*XTD*8;             // 0.59 MB (dead before dout2)
    unsigned* dwb2 = (unsigned*)(dout2 + (size_t)16*128*128*64);  // 73.7 KB
    unsigned* cwb2 = dwb2 + 18432;                          // 32.8 KB
    unsigned* pwb  = cwb2 + 8192;                           // 36.9 KB

    k_prep        <<<dim3(1740),    256, 0, stream>>>(w1,w2,w3,w4, dw, cw, pw,
                                                      (uint4*)xt, wbt, dwb2, cwb2, pwb);
    k_xprep       <<<dim3(128,4),   256, 0, stream>>>(x, xt);
    k_branch_mfma <<<dim3(1024),    256, 0, stream>>>(xt, wbt, b1,b2,b3,b4, feats2);
    k_offset_mfma <<<dim3(2048),    256, 0, stream>>>(feats2, pwb, pb, offs);
    k_deform_mfma <<<dim3(2048),    256, 0, stream>>>(feats2, offs, dwb2, db, dout2);
    k_combine_mfma<<<dim3(128,4),   256, 0, stream>>>(dout2, cwb2, cb, out);
}

// Round 9
// 329.276 us; speedup vs baseline: 1.3439x; 1.3439x over previous
//
#include <hip/hip_runtime.h>
#include <hip/hip_bf16.h>

#define H 128
#define W 128
#define CIN 128
#define COUT 64
#define HW (H*W)
#define XW 130                    // padded spatial dim (y,x in [0,129])
#define FSL (XW*XW*64)            // feats2 elems per zb slice (NHWC bf16)
#define XTD 144                   // xt padded dim

typedef __hip_bfloat16 bf16;
typedef __attribute__((ext_vector_type(8)))  short s16x8;
typedef __attribute__((ext_vector_type(16))) float f32x16;

__device__ __forceinline__ float b2f(bf16 v){ return __bfloat162float(v); }
__device__ __forceinline__ bf16  f2b(float v){ return __float2bfloat16(v); }
__device__ __forceinline__ unsigned pack2(float a, float b){
    unsigned short ua = __builtin_bit_cast(unsigned short, f2b(a));
    unsigned short ub = __builtin_bit_cast(unsigned short, f2b(b));
    return (unsigned)ua | ((unsigned)ub << 16);
}
__device__ __forceinline__ unsigned short b16u(float v){
    return __builtin_bit_cast(unsigned short, f2b(v));
}
__device__ __forceinline__ float2 up2(unsigned u){
    float lo = __builtin_bit_cast(float, u << 16);
    float hi = __builtin_bit_cast(float, u & 0xFFFF0000u);
    return make_float2(lo, hi);
}

// ---------------------------------------------------------------------------
// k_prep: [0,1024) zero xt2; [1024,1600) wbt; [1600,1672) dwb2;
//         [1672,1704) cwb2; [1704,1740) pwb
// ---------------------------------------------------------------------------
__global__ __launch_bounds__(256) void k_prep(
    const float* __restrict__ w1, const float* __restrict__ w2,
    const float* __restrict__ w3, const float* __restrict__ w4,
    const float* __restrict__ dw, const float* __restrict__ cw,
    const float* __restrict__ pw,
    uint4* __restrict__ xt4, unsigned* __restrict__ wbt,
    unsigned* __restrict__ dwb2, unsigned* __restrict__ cwb2,
    unsigned* __restrict__ pwb)
{
    int bid = blockIdx.x;
    int t = threadIdx.x;
    if (bid < 1024){
        const int n4 = (4*XTD*XTD*64)/4;        // 1327104
        for (int i = bid*256 + t; i < n4; i += 1024*256)
            xt4[i] = make_uint4(0,0,0,0);
    } else if (bid < 1600){
        int tid = (bid-1024)*256 + t;            // 147456 = 4*8*9*64*8
        int cpl = tid & 7;
        int oc  = (tid >> 3) & 63;
        int tap = (tid >> 9) % 9;
        int cg  = (tid / 4608) & 7;
        int d   = tid / 36864;
        const float* wt = (d==0)?w1:(d==1)?w2:(d==2)?w3:w4;
        int c = cg*8 + cpl;
        wbt[tid] = pack2(wt[((size_t)oc*CIN + 2*c  )*9 + tap],
                         wt[((size_t)oc*CIN + 2*c+1)*9 + tap]);
    } else if (bid < 1672){
        int i = (bid-1600)*256 + t;              // 18432: dwb2[n][oc][cp32]
        int n = i>>11, oc = (i>>5)&63, cp = i&31;
        dwb2[i] = pack2(dw[((size_t)oc*64 + 2*cp  )*9 + n],
                        dw[((size_t)oc*64 + 2*cp+1)*9 + n]);
    } else if (bid < 1704){
        int i = (bid-1672)*256 + t;              // 8192: cwb2[oc][cp128]
        int oc = i>>7, cp = i&127;
        cwb2[i] = pack2(cw[(size_t)oc*256 + 2*cp], cw[(size_t)oc*256 + 2*cp+1]);
    } else {
        int i = (bid-1704)*256 + t;              // 9216
        int cl = i & 3, oc = (i>>2)&31, hf = (i>>7)&1, cq = (i>>8)&3, tap = i>>10;
        int c = cq*16 + hf*8 + cl*2;
        unsigned v = 0u;
        if (oc < 18)
            v = pack2(pw[((size_t)oc*64 + c  )*9 + tap],
                      pw[((size_t)oc*64 + c+1)*9 + tap]);
        pwb[i] = v;
    }
}

// ---------------------------------------------------------------------------
// xprep: xt2[b][cg 8][y+8][col+8][cpl 8] u32 (interior). grid (128 y, 4 b).
// ---------------------------------------------------------------------------
__global__ __launch_bounds__(256) void k_xprep(
    const float* __restrict__ x, unsigned* __restrict__ xt)
{
    int y = blockIdx.x, b = blockIdx.y;
    int t = threadIdx.x;
    __shared__ float xsm[64*131];
    for (int ci0 = 0; ci0 < 128; ci0 += 64){
        for (int i=0;i<32;i++){
            int idx = t + 256*i;
            int col = idx & 127, ci = idx >> 7;
            xsm[ci*131 + col] = x[(((size_t)b*CIN + ci0+ci)*H + y)*W + col];
        }
        __syncthreads();
        for (int i=0;i<16;i++){
            int idx = t + 256*i;
            int cpg = idx & 31, col = idx >> 5;
            int cgg = (ci0 >> 4) + (cpg >> 3);
            int cpl = cpg & 7;
            unsigned u = pack2(xsm[(2*cpg)*131 + col], xsm[(2*cpg+1)*131 + col]);
            xt[((((size_t)b*8 + cgg)*XTD + y+8)*XTD + col+8)*8 + cpl] = u;
        }
        __syncthreads();
    }
}

// ---------------------------------------------------------------------------
// K1: dilated 3x3 conv via bf16 MFMA implicit GEMM. grid 1024 1-D, XCD swizzle.
// ---------------------------------------------------------------------------
__global__ __launch_bounds__(256,2) void k_branch_mfma(
    const unsigned* __restrict__ xt, const unsigned* __restrict__ wbt,
    const float* __restrict__ b1, const float* __restrict__ b2,
    const float* __restrict__ b3, const float* __restrict__ b4,
    bf16* __restrict__ feats2)
{
    int bid = blockIdx.x;
    int xcd = bid & 7;
    int j   = bid >> 3;
    int zb  = xcd + 8*(j & 1);
    int hp  = j >> 1;
    int d = zb >> 2, b = zb & 3;
    int dil = 2*d + 1;
    int h0 = hp*2;
    const float* bs = (d==0)?b1:(d==1)?b2:(d==2)?b3:b4;
    const float scale = (float)dil;

    __shared__ unsigned smem[10368 + 6912];
    unsigned* As = smem;
    unsigned* Bs = smem + 10368;
    const unsigned short* As16 = (const unsigned short*)As;
    const unsigned short* Bs16 = (const unsigned short*)Bs;

    int t = threadIdx.x;
    int lane = t & 63;
    int w = t >> 6;
    int l31 = lane & 31;
    int half = lane >> 5;

    bf16* fb = feats2 + (size_t)zb*FSL;
    if (t < 32){
        int yy = h0 + 1 + (t>>4);
        int side = (t>>3)&1;
        int q = t & 7;
        uint4 z = make_uint4(0,0,0,0);
        *(uint4*)((unsigned short*)fb + ((size_t)yy*XW + side*129)*64 + q*8) = z;
    }
    if (hp == 0){
        uint4 z = make_uint4(0,0,0,0);
        for (int i=t; i<2080; i+=256){
            int row = i / 1040;
            int r = i % 1040;
            int xx = r >> 3, q = r & 7;
            *(uint4*)((unsigned short*)fb + ((size_t)(row*129)*XW + xx)*64 + q*8) = z;
        }
    }

    f32x16 acc[2][2];
    #pragma unroll
    for (int i=0;i<2;i++)
      #pragma unroll
      for (int jj=0;jj<2;jj++)
        #pragma unroll
        for (int e=0;e<16;e++) acc[i][jj][e] = 0.f;

    const unsigned* xtb_b = xt + (size_t)b*8*XTD*XTD*8;
    int r = w >> 1;
    int pxb = (w & 1) * 64;

    for (int cg=0; cg<8; cg++){
        const unsigned* xs_cg = xtb_b + (size_t)cg*XTD*XTD*8;
        #pragma unroll
        for (int i=0;i<7;i++){
            int idx4 = t + 256*i;
            if (idx4 < 1728){
                int cp4 = idx4 & 1;
                int s   = (idx4 >> 1) % 144;
                int row6= idx4 / 288;
                int ky = row6 >> 1, rr = row6 & 1;
                int yy = h0 + rr + (ky-1)*dil + 8;
                uint4 v = *(const uint4*)(xs_cg + ((size_t)yy*XTD + (s + 8 - dil))*8 + cp4*4);
                *(uint4*)&As[(row6*144 + s)*12 + cp4*4] = v;
            }
        }
        const unsigned* wb_cg = wbt + ((size_t)d*8 + cg)*4608;
        #pragma unroll
        for (int i=0;i<5;i++){
            int idx4 = t + 256*i;
            if (idx4 < 1152){
                int cp4 = idx4 & 1;
                int oc  = (idx4 >> 1) & 63;
                int tap = idx4 >> 7;
                uint4 v = *(const uint4*)(wb_cg + ((size_t)tap*64 + oc)*8 + cp4*4);
                *(uint4*)&Bs[(tap*64 + oc)*12 + cp4*4] = v;
            }
        }
        __syncthreads();
        #pragma unroll
        for (int tap=0; tap<9; tap++){
            int ky = tap/3, kx = tap%3;
            int rowb = (ky*2 + r)*144;
            s16x8 a0 = *(const s16x8*)(As16 + (rowb + pxb      + l31 + kx*dil)*24 + half*8);
            s16x8 a1 = *(const s16x8*)(As16 + (rowb + pxb + 32 + l31 + kx*dil)*24 + half*8);
            s16x8 bb0 = *(const s16x8*)(Bs16 + (tap*64      + l31)*24 + half*8);
            s16x8 bb1 = *(const s16x8*)(Bs16 + (tap*64 + 32 + l31)*24 + half*8);
            acc[0][0] = __builtin_amdgcn_mfma_f32_32x32x16_bf16(a0, bb0, acc[0][0], 0,0,0);
            acc[0][1] = __builtin_amdgcn_mfma_f32_32x32x16_bf16(a0, bb1, acc[0][1], 0,0,0);
            acc[1][0] = __builtin_amdgcn_mfma_f32_32x32x16_bf16(a1, bb0, acc[1][0], 0,0,0);
            acc[1][1] = __builtin_amdgcn_mfma_f32_32x32x16_bf16(a1, bb1, acc[1][1], 0,0,0);
        }
        __syncthreads();
    }

    unsigned short* ep = (unsigned short*)smem;
    float bias0 = bs[l31], bias1 = bs[32 + l31];
    #pragma unroll
    for (int i=0;i<2;i++){
      #pragma unroll
      for (int jj=0;jj<2;jj++){
        int oc = jj*32 + l31;
        float bj = jj ? bias1 : bias0;
        #pragma unroll
        for (int rg=0; rg<4; rg++){
            int m0 = 64*w + 32*i + 8*rg + 4*half;
            #pragma unroll
            for (int e=0;e<4;e++)
                ep[(m0+e)*64 + oc] = b16u((acc[i][jj][4*rg+e] + bj)*scale);
        }
      }
    }
    __syncthreads();
    {
        int row = t >> 7, pxm = t & 127;
        unsigned short* drow = (unsigned short*)fb + ((size_t)(h0+1+row)*XW + pxm + 1)*64;
        const unsigned short* srow = ep + t*64;
        #pragma unroll
        for (int q=0;q<8;q++)
            *(uint4*)(drow + q*8) = *(const uint4*)(srow + q*8);
    }
}

// ---------------------------------------------------------------------------
// K2: 3x3 conv 64 -> 18 (offsets) via bf16 MFMA, XCD swizzle.
// ---------------------------------------------------------------------------
__global__ __launch_bounds__(256,2) void k_offset_mfma(
    const bf16* __restrict__ feats2,
    const unsigned* __restrict__ pwb,   // [tap][cq][hf][oc32][cl4] u32
    const float* __restrict__ pb,
    bf16* __restrict__ offs)
{
    int bid = blockIdx.x;
    int xcd  = bid & 7;
    int h    = (bid >> 3) & 127;
    int pass = bid >> 10;
    int zb   = xcd + 8*pass;

    int t = threadIdx.x;
    int lane = t & 63, w = t >> 6;
    int l31 = lane & 31, half = lane >> 5;

    __shared__ unsigned short xs[3*132*68];   // 53.9 KB

    const unsigned short* fin = (const unsigned short*)(feats2 + (size_t)zb*FSL);
    for (int i=t; i<3120; i+=256){
        int row = i / 1040;
        int r   = i % 1040;
        int col = r >> 3, q = r & 7;
        uint4 v = *(const uint4*)(fin + ((size_t)(h+row)*XW + col)*64 + q*8);
        *(uint4*)&xs[(row*132 + col)*68 + q*8] = v;
    }
    __syncthreads();

    f32x16 acc;
    #pragma unroll
    for (int e=0;e<16;e++) acc[e] = 0.f;

    int pxw = 32*w + l31;
    #pragma unroll
    for (int tap=0; tap<9; tap++){
        int ky = tap/3, kx = tap%3;
        const unsigned short* arow = &xs[(ky*132 + pxw + kx)*68 + half*8];
        const unsigned* brow = pwb + (((size_t)tap*4)*2 + half)*128 + l31*4;
        #pragma unroll
        for (int cq=0; cq<4; cq++){
            s16x8 a  = *(const s16x8*)(arow + cq*16);
            s16x8 b0 = *(const s16x8*)(brow + cq*256);
            acc = __builtin_amdgcn_mfma_f32_32x32x16_bf16(a, b0, acc, 0,0,0);
        }
    }
    __syncthreads();

    unsigned short* ep = (unsigned short*)xs;   // [oc 18][132 pad]
    if (l31 < 18){
        float bias = pb[l31];
        #pragma unroll
        for (int rg=0; rg<4; rg++){
            int m0 = 32*w + 4*half + 8*rg;
            #pragma unroll
            for (int e=0;e<4;e++)
                ep[l31*132 + m0+e] = b16u(acc[4*rg+e] + bias);
        }
    }
    __syncthreads();
    unsigned short* obase = (unsigned short*)(offs + (size_t)zb*18*HW) ;
    for (int i=t; i<288; i+=256){
        int oc = i >> 4, sg = i & 15;
        *(uint4*)(obase + (size_t)oc*HW + h*W + sg*8) = *(const uint4*)(ep + oc*132 + sg*8);
    }
}

// ---------------------------------------------------------------------------
// K3a: deform sampling + dw einsum via bf16 MFMA — CHANNEL-MAJOR gather.
// grid 2048 1-D, XCD swizzle. Gather phase: 8 lanes per pixel (lane cq=t&7
// takes 8 channels) so each corner load instruction touches 8 cache lines,
// not 64. Blended packs go to A-frag LDS (row stride 516 u32: conflict-free
// strided ds_write_b128). MFMA phase identical to proven R7 addressing.
// ---------------------------------------------------------------------------
__global__ __launch_bounds__(256,4) void k_deform_mfma(
    const bf16* __restrict__ feats2,
    const bf16* __restrict__ offs,
    const unsigned* __restrict__ dwb2,  // [n][oc][cp32] u32
    const float* __restrict__ db,
    bf16* __restrict__ dout2)
{
    int bid = blockIdx.x;
    int xcd  = bid & 7;
    int h    = (bid >> 3) & 127;
    int pass = bid >> 10;
    int zb   = xcd + 8*pass;

    int t = threadIdx.x;
    int lane = t & 63, w = t >> 6;
    int l31 = lane & 31, half = lane >> 5;
    int pxg = t >> 3;                 // 0..31, pixel group (gather phase)
    int cq  = t & 7;                  // which 8-ch slice of the 64-ch line
    int sub_w = cq >> 1;              // A-frag sub (0..3)
    int hf8   = cq & 1;               // A-frag half (0..1)

    #define AROW 516                   // u32 row stride (8 rows)
    __shared__ unsigned smem_d[8*AROW + 2304];   // 16.1 KB A + 9 KB B
    unsigned* Asu = smem_d;
    unsigned* Bsu = smem_d + 8*AROW;

    const bf16* obase = offs + (size_t)zb*18*HW + h*W;
    const unsigned short* fbase = (const unsigned short*)(feats2 + (size_t)zb*FSL);

    f32x16 acc0, acc1;
    #pragma unroll
    for (int e=0;e<16;e++){ acc0[e]=0.f; acc1[e]=0.f; }

    for (int n=0; n<9; n++){
        // stage B for this n
        const uint4* dsrc = (const uint4*)(dwb2 + n*2048);
        #pragma unroll
        for (int i=0;i<2;i++){
            int j = t + 256*i;
            int idx4 = j*4;
            int oc = idx4 >> 5, cp = idx4 & 31;
            *(uint4*)&Bsu[oc*36 + cp] = dsrc[j];
        }
        // gather: 4 slots x (this lane: pixel slot*32+pxg, channels cq*8..+8)
        #pragma unroll
        for (int s=0; s<4; s++){
            int px = s*32 + pxg;
            float offy = b2f(obase[n*HW + px]);
            float offx = b2f(obase[(n+9)*HW + px]);
            float py  = (float)(h + n/3) + offy;
            float pxf = (float)(px + n%3) + offx;
            float fy = floorf(py), fx = floorf(pxf);
            float lty = fminf(fmaxf(fy,     0.f),129.f);
            float ltx = fminf(fmaxf(fx,     0.f),129.f);
            float rby = fminf(fmaxf(fy+1.f, 0.f),129.f);
            float rbx = fminf(fmaxf(fx+1.f, 0.f),129.f);
            float pyc = fminf(fmaxf(py,     0.f),129.f);
            float pxc = fminf(fmaxf(pxf,    0.f),129.f);
            float ay = 1.f + (lty-pyc), by = 1.f - (rby-pyc);
            float ax = 1.f + (ltx-pxc), bx = 1.f - (rbx-pxc);
            float glt = ay*ax, glb = ay*bx, grt = by*ax, grb = by*bx;
            int base = ((int)lty*XW + (int)ltx)*64;
            int dxo  = ((int)rbx - (int)ltx)*64;
            int dyo  = ((int)rby - (int)lty)*XW*64;

            const unsigned short* fc = fbase + base + cq*8;
            unsigned LT[4], LB[4], RT[4], RB[4];
            *(uint4*)LT = *(const uint4*)(fc);
            *(uint4*)LB = *(const uint4*)(fc+dxo);
            *(uint4*)RT = *(const uint4*)(fc+dyo);
            *(uint4*)RB = *(const uint4*)(fc+dyo+dxo);
            unsigned pk[4];
            #pragma unroll
            for (int jq=0;jq<4;jq++){
                float2 a = up2(LT[jq]), bq = up2(LB[jq]);
                float2 c = up2(RT[jq]), dq = up2(RB[jq]);
                float slo = glt*a.x + glb*bq.x + grt*c.x + grb*dq.x;
                float shi = glt*a.y + glb*bq.y + grt*c.y + grb*dq.y;
                pk[jq] = pack2(slo, shi);
            }
            uint4 av; av.x=pk[0]; av.y=pk[1]; av.z=pk[2]; av.w=pk[3];
            *(uint4*)&Asu[(sub_w*2 + hf8)*AROW + px*4] = av;
        }
        __syncthreads();
        const unsigned short* As16 = (const unsigned short*)Asu;
        const unsigned short* Bs16 = (const unsigned short*)Bsu;
        #pragma unroll
        for (int s=0;s<4;s++){
            s16x8 a  = *(const s16x8*)(As16 + (s*2+half)*(AROW*2) + (32*w + l31)*8);
            s16x8 b0 = *(const s16x8*)(Bs16 + (l31*36 + s*8 + half*4)*2);
            s16x8 b1 = *(const s16x8*)(Bs16 + ((32+l31)*36 + s*8 + half*4)*2);
            acc0 = __builtin_amdgcn_mfma_f32_32x32x16_bf16(a, b0, acc0, 0,0,0);
            acc1 = __builtin_amdgcn_mfma_f32_32x32x16_bf16(a, b1, acc1, 0,0,0);
        }
        __syncthreads();
    }

    // epilogue: +db, ep[px][oc] u16 == dout2 row layout, straight copy out
    unsigned short* ep = (unsigned short*)smem_d;   // 16 KB overlay (safe: barrier above)
    #pragma unroll
    for (int nt=0; nt<2; nt++){
        int oc = nt*32 + l31;
        float bias = db[oc];
        const f32x16& A = nt ? acc1 : acc0;
        #pragma unroll
        for (int rg=0; rg<4; rg++){
            int m0 = 32*w + 4*half + 8*rg;
            #pragma unroll
            for (int e=0;e<4;e++)
                ep[(m0+e)*64 + oc] = b16u(A[4*rg+e] + bias);
        }
    }
    __syncthreads();
    uint4* dst = (uint4*)((unsigned short*)dout2 + ((size_t)zb*128 + h)*(128*64));
    #pragma unroll
    for (int i=0;i<4;i++)
        dst[t + 256*i] = ((const uint4*)ep)[t + 256*i];
    #undef AROW
}

// ---------------------------------------------------------------------------
// K3b: 1x1 conv 256 -> 64 + cb + ReLU via bf16 MFMA. grid (128 h, 4 b).
// ---------------------------------------------------------------------------
__global__ __launch_bounds__(256,2) void k_combine_mfma(
    const bf16* __restrict__ dout2,
    const unsigned* __restrict__ cwb2,  // [oc][cp128] u32
    const float* __restrict__ cb,
    float* __restrict__ out)
{
    int h = blockIdx.x, b = blockIdx.y;
    int t = threadIdx.x;
    int px = t & 127, hf = t >> 7;
    int lane = t & 63, w = t >> 6, l31 = lane & 31, half = lane >> 5;

    __shared__ unsigned Bsu[64*132];
    __shared__ unsigned Asu2[1024];

    for (int i=t; i<8192; i+=256){
        int oc = i>>7, cp = i&127;
        Bsu[oc*132 + cp] = cwb2[i];
    }
    f32x16 acc0, acc1;
    #pragma unroll
    for (int e=0;e<16;e++){ acc0[e]=0.f; acc1[e]=0.f; }

    const unsigned short* dbase0 = (const unsigned short*)dout2;
    size_t rowsel = ((size_t)b*128 + h)*128 + px;
    uint4 v = *(const uint4*)(dbase0 + rowsel*64 + hf*8);
    for (int kc=0; kc<16; kc++){
        *(uint4*)&Asu2[(hf*128+px)*4] = v;
        __syncthreads();
        if (kc < 15){
            int kn = kc+1;
            int d = kn>>2, c16 = kn&3;
            v = *(const uint4*)(dbase0 + ((size_t)d*4*128*128*64 + rowsel*64) + c16*16 + hf*8);
        }
        const unsigned short* As16 = (const unsigned short*)Asu2;
        const unsigned short* Bs16 = (const unsigned short*)Bsu;
        s16x8 a  = *(const s16x8*)(As16 + (half*128 + 32*w + l31)*8);
        s16x8 b0 = *(const s16x8*)(Bs16 + (l31*132 + kc*8 + half*4)*2);
        s16x8 b1 = *(const s16x8*)(Bs16 + ((32+l31)*132 + kc*8 + half*4)*2);
        acc0 = __builtin_amdgcn_mfma_f32_32x32x16_bf16(a, b0, acc0, 0,0,0);
        acc1 = __builtin_amdgcn_mfma_f32_32x32x16_bf16(a, b1, acc1, 0,0,0);
        __syncthreads();
    }
    float* ep = (float*)Bsu;
    #pragma unroll
    for (int nt=0; nt<2; nt++){
        int oc = nt*32 + l31;
        float bias = cb[oc];
        const f32x16& A = nt ? acc1 : acc0;
        #pragma unroll
        for (int rg=0; rg<4; rg++){
            int m0 = 32*w + 4*half + 8*rg;
            #pragma unroll
            for (int e=0;e<4;e++)
                ep[oc*132 + m0+e] = fmaxf(A[4*rg+e] + bias, 0.f);
        }
    }
    __syncthreads();
    for (int i=t; i<2048; i+=256){
        int oc = i>>5, sg = i&31;
        *(uint4*)&out[(((size_t)b*64+oc)*128 + h)*128 + sg*4] = *(const uint4*)&ep[oc*132 + sg*4];
    }
}

extern "C" void kernel_launch(void* const* d_in, const int* in_sizes, int n_in,
                              void* d_out, int out_size, void* d_ws, size_t ws_size,
                              hipStream_t stream) {
    const float* x  = (const float*)d_in[0];
    const float* w1 = (const float*)d_in[1];
    const float* b1 = (const float*)d_in[2];
    const float* w2 = (const float*)d_in[3];
    const float* b2 = (const float*)d_in[4];
    const float* w3 = (const float*)d_in[5];
    const float* b3 = (const float*)d_in[6];
    const float* w4 = (const float*)d_in[7];
    const float* b4 = (const float*)d_in[8];
    const float* pw = (const float*)d_in[9];
    const float* pb = (const float*)d_in[10];
    const float* dw = (const float*)d_in[11];
    const float* db = (const float*)d_in[12];
    const float* cw = (const float*)d_in[13];
    const float* cb = (const float*)d_in[14];
    float* out = (float*)d_out;

    bf16* feats2 = (bf16*)d_ws;                             // 34.6 MB
    bf16* offs   = feats2 + (size_t)16*FSL;                 // 9.4 MB
    bf16* region2 = offs + (size_t)16*18*HW;
    bf16* dout2  = region2;                                 // 33.55 MB
    unsigned* xt  = (unsigned*)region2;                     // 21.2 MB (dead before dout2)
    unsigned* wbt = xt + (size_t)4*8*XTD*XTD*8;             // 0.59 MB (dead before dout2)
    unsigned* dwb2 = (unsigned*)(dout2 + (size_t)16*128*128*64);  // 73.7 KB
    unsigned* cwb2 = dwb2 + 18432;                          // 32.8 KB
    unsigned* pwb  = cwb2 + 8192;                           // 36.9 KB

    k_prep        <<<dim3(1740),    256, 0, stream>>>(w1,w2,w3,w4, dw, cw, pw,
                                                      (uint4*)xt, wbt, dwb2, cwb2, pwb);
    k_xprep       <<<dim3(128,4),   256, 0, stream>>>(x, xt);
    k_branch_mfma <<<dim3(1024),    256, 0, stream>>>(xt, wbt, b1,b2,b3,b4, feats2);
    k_offset_mfma <<<dim3(2048),    256, 0, stream>>>(feats2, pwb, pb, offs);
    k_deform_mfma <<<dim3(2048),    256, 0, stream>>>(feats2, offs, dwb2, db, dout2);
    k_combine_mfma<<<dim3(128,4),   256, 0, stream>>>(dout2, cwb2, cb, out);
}

// Round 11
// 325.799 us; speedup vs baseline: 1.3583x; 1.0107x over previous
//
#include <hip/hip_runtime.h>
#include <hip/hip_bf16.h>

#define H 128
#define W 128
#define CIN 128
#define COUT 64
#define HW (H*W)
#define XW 130                    // padded spatial dim (y,x in [0,129])
#define FSL (XW*XW*64)            // feats2 elems per zb slice (NHWC bf16)
#define XTD 144                   // xt padded dim

typedef __hip_bfloat16 bf16;
typedef __attribute__((ext_vector_type(8)))  short s16x8;
typedef __attribute__((ext_vector_type(16))) float f32x16;

__device__ __forceinline__ float b2f(bf16 v){ return __bfloat162float(v); }
__device__ __forceinline__ bf16  f2b(float v){ return __float2bfloat16(v); }
__device__ __forceinline__ unsigned pack2(float a, float b){
    unsigned short ua = __builtin_bit_cast(unsigned short, f2b(a));
    unsigned short ub = __builtin_bit_cast(unsigned short, f2b(b));
    return (unsigned)ua | ((unsigned)ub << 16);
}
__device__ __forceinline__ unsigned short b16u(float v){
    return __builtin_bit_cast(unsigned short, f2b(v));
}
__device__ __forceinline__ float2 up2(unsigned u){
    float lo = __builtin_bit_cast(float, u << 16);
    float hi = __builtin_bit_cast(float, u & 0xFFFF0000u);
    return make_float2(lo, hi);
}

// ---------------------------------------------------------------------------
// k_prep: [0,1024) zero xt2; [1024,1600) wbt; [1600,1672) dwb2;
//         [1672,1704) cwb2; [1704,1740) pwb      (R9 verbatim)
// ---------------------------------------------------------------------------
__global__ __launch_bounds__(256) void k_prep(
    const float* __restrict__ w1, const float* __restrict__ w2,
    const float* __restrict__ w3, const float* __restrict__ w4,
    const float* __restrict__ dw, const float* __restrict__ cw,
    const float* __restrict__ pw,
    uint4* __restrict__ xt4, unsigned* __restrict__ wbt,
    unsigned* __restrict__ dwb2, unsigned* __restrict__ cwb2,
    unsigned* __restrict__ pwb)
{
    int bid = blockIdx.x;
    int t = threadIdx.x;
    if (bid < 1024){
        const int n4 = (4*XTD*XTD*64)/4;        // 1327104
        for (int i = bid*256 + t; i < n4; i += 1024*256)
            xt4[i] = make_uint4(0,0,0,0);
    } else if (bid < 1600){
        int tid = (bid-1024)*256 + t;            // 147456 = 4*8*9*64*8
        int cpl = tid & 7;
        int oc  = (tid >> 3) & 63;
        int tap = (tid >> 9) % 9;
        int cg  = (tid / 4608) & 7;
        int d   = tid / 36864;
        const float* wt = (d==0)?w1:(d==1)?w2:(d==2)?w3:w4;
        int c = cg*8 + cpl;
        wbt[tid] = pack2(wt[((size_t)oc*CIN + 2*c  )*9 + tap],
                         wt[((size_t)oc*CIN + 2*c+1)*9 + tap]);
    } else if (bid < 1672){
        int i = (bid-1600)*256 + t;              // 18432: dwb2[n][oc][cp32]
        int n = i>>11, oc = (i>>5)&63, cp = i&31;
        dwb2[i] = pack2(dw[((size_t)oc*64 + 2*cp  )*9 + n],
                        dw[((size_t)oc*64 + 2*cp+1)*9 + n]);
    } else if (bid < 1704){
        int i = (bid-1672)*256 + t;              // 8192: cwb2[oc][cp128]
        int oc = i>>7, cp = i&127;
        cwb2[i] = pack2(cw[(size_t)oc*256 + 2*cp], cw[(size_t)oc*256 + 2*cp+1]);
    } else {
        int i = (bid-1704)*256 + t;              // 9216
        int cl = i & 3, oc = (i>>2)&31, hf = (i>>7)&1, cq = (i>>8)&3, tap = i>>10;
        int c = cq*16 + hf*8 + cl*2;
        unsigned v = 0u;
        if (oc < 18)
            v = pack2(pw[((size_t)oc*64 + c  )*9 + tap],
                      pw[((size_t)oc*64 + c+1)*9 + tap]);
        pwb[i] = v;
    }
}

// ---------------------------------------------------------------------------
// xprep: xt2[b][cg 8][y+8][col+8][cpl 8] u32 (interior). grid (128 y, 4 b).
// ---------------------------------------------------------------------------
__global__ __launch_bounds__(256) void k_xprep(
    const float* __restrict__ x, unsigned* __restrict__ xt)
{
    int y = blockIdx.x, b = blockIdx.y;
    int t = threadIdx.x;
    __shared__ float xsm[64*131];
    for (int ci0 = 0; ci0 < 128; ci0 += 64){
        for (int i=0;i<32;i++){
            int idx = t + 256*i;
            int col = idx & 127, ci = idx >> 7;
            xsm[ci*131 + col] = x[(((size_t)b*CIN + ci0+ci)*H + y)*W + col];
        }
        __syncthreads();
        for (int i=0;i<16;i++){
            int idx = t + 256*i;
            int cpg = idx & 31, col = idx >> 5;
            int cgg = (ci0 >> 4) + (cpg >> 3);
            int cpl = cpg & 7;
            unsigned u = pack2(xsm[(2*cpg)*131 + col], xsm[(2*cpg+1)*131 + col]);
            xt[((((size_t)b*8 + cgg)*XTD + y+8)*XTD + col+8)*8 + cpl] = u;
        }
        __syncthreads();
    }
}

// ---------------------------------------------------------------------------
// K1: dilated 3x3 conv via bf16 MFMA implicit GEMM. grid 1024 1-D, XCD swizzle.
// ---------------------------------------------------------------------------
__global__ __launch_bounds__(256,2) void k_branch_mfma(
    const unsigned* __restrict__ xt, const unsigned* __restrict__ wbt,
    const float* __restrict__ b1, const float* __restrict__ b2,
    const float* __restrict__ b3, const float* __restrict__ b4,
    bf16* __restrict__ feats2)
{
    int bid = blockIdx.x;
    int xcd = bid & 7;
    int j   = bid >> 3;
    int zb  = xcd + 8*(j & 1);
    int hp  = j >> 1;
    int d = zb >> 2, b = zb & 3;
    int dil = 2*d + 1;
    int h0 = hp*2;
    const float* bs = (d==0)?b1:(d==1)?b2:(d==2)?b3:b4;
    const float scale = (float)dil;

    __shared__ unsigned smem[10368 + 6912];
    unsigned* As = smem;
    unsigned* Bs = smem + 10368;
    const unsigned short* As16 = (const unsigned short*)As;
    const unsigned short* Bs16 = (const unsigned short*)Bs;

    int t = threadIdx.x;
    int lane = t & 63;
    int w = t >> 6;
    int l31 = lane & 31;
    int half = lane >> 5;

    bf16* fb = feats2 + (size_t)zb*FSL;
    if (t < 32){
        int yy = h0 + 1 + (t>>4);
        int side = (t>>3)&1;
        int q = t & 7;
        uint4 z = make_uint4(0,0,0,0);
        *(uint4*)((unsigned short*)fb + ((size_t)yy*XW + side*129)*64 + q*8) = z;
    }
    if (hp == 0){
        uint4 z = make_uint4(0,0,0,0);
        for (int i=t; i<2080; i+=256){
            int row = i / 1040;
            int r = i % 1040;
            int xx = r >> 3, q = r & 7;
            *(uint4*)((unsigned short*)fb + ((size_t)(row*129)*XW + xx)*64 + q*8) = z;
        }
    }

    f32x16 acc[2][2];
    #pragma unroll
    for (int i=0;i<2;i++)
      #pragma unroll
      for (int jj=0;jj<2;jj++)
        #pragma unroll
        for (int e=0;e<16;e++) acc[i][jj][e] = 0.f;

    const unsigned* xtb_b = xt + (size_t)b*8*XTD*XTD*8;
    int r = w >> 1;
    int pxb = (w & 1) * 64;

    for (int cg=0; cg<8; cg++){
        const unsigned* xs_cg = xtb_b + (size_t)cg*XTD*XTD*8;
        #pragma unroll
        for (int i=0;i<7;i++){
            int idx4 = t + 256*i;
            if (idx4 < 1728){
                int cp4 = idx4 & 1;
                int s   = (idx4 >> 1) % 144;
                int row6= idx4 / 288;
                int ky = row6 >> 1, rr = row6 & 1;
                int yy = h0 + rr + (ky-1)*dil + 8;
                uint4 v = *(const uint4*)(xs_cg + ((size_t)yy*XTD + (s + 8 - dil))*8 + cp4*4);
                *(uint4*)&As[(row6*144 + s)*12 + cp4*4] = v;
            }
        }
        const unsigned* wb_cg = wbt + ((size_t)d*8 + cg)*4608;
        #pragma unroll
        for (int i=0;i<5;i++){
            int idx4 = t + 256*i;
            if (idx4 < 1152){
                int cp4 = idx4 & 1;
                int oc  = (idx4 >> 1) & 63;
                int tap = idx4 >> 7;
                uint4 v = *(const uint4*)(wb_cg + ((size_t)tap*64 + oc)*8 + cp4*4);
                *(uint4*)&Bs[(tap*64 + oc)*12 + cp4*4] = v;
            }
        }
        __syncthreads();
        #pragma unroll
        for (int tap=0; tap<9; tap++){
            int ky = tap/3, kx = tap%3;
            int rowb = (ky*2 + r)*144;
            s16x8 a0 = *(const s16x8*)(As16 + (rowb + pxb      + l31 + kx*dil)*24 + half*8);
            s16x8 a1 = *(const s16x8*)(As16 + (rowb + pxb + 32 + l31 + kx*dil)*24 + half*8);
            s16x8 bb0 = *(const s16x8*)(Bs16 + (tap*64      + l31)*24 + half*8);
            s16x8 bb1 = *(const s16x8*)(Bs16 + (tap*64 + 32 + l31)*24 + half*8);
            acc[0][0] = __builtin_amdgcn_mfma_f32_32x32x16_bf16(a0, bb0, acc[0][0], 0,0,0);
            acc[0][1] = __builtin_amdgcn_mfma_f32_32x32x16_bf16(a0, bb1, acc[0][1], 0,0,0);
            acc[1][0] = __builtin_amdgcn_mfma_f32_32x32x16_bf16(a1, bb0, acc[1][0], 0,0,0);
            acc[1][1] = __builtin_amdgcn_mfma_f32_32x32x16_bf16(a1, bb1, acc[1][1], 0,0,0);
        }
        __syncthreads();
    }

    unsigned short* ep = (unsigned short*)smem;
    float bias0 = bs[l31], bias1 = bs[32 + l31];
    #pragma unroll
    for (int i=0;i<2;i++){
      #pragma unroll
      for (int jj=0;jj<2;jj++){
        int oc = jj*32 + l31;
        float bj = jj ? bias1 : bias0;
        #pragma unroll
        for (int rg=0; rg<4; rg++){
            int m0 = 64*w + 32*i + 8*rg + 4*half;
            #pragma unroll
            for (int e=0;e<4;e++)
                ep[(m0+e)*64 + oc] = b16u((acc[i][jj][4*rg+e] + bj)*scale);
        }
      }
    }
    __syncthreads();
    {
        int row = t >> 7, pxm = t & 127;
        unsigned short* drow = (unsigned short*)fb + ((size_t)(h0+1+row)*XW + pxm + 1)*64;
        const unsigned short* srow = ep + t*64;
        #pragma unroll
        for (int q=0;q<8;q++)
            *(uint4*)(drow + q*8) = *(const uint4*)(srow + q*8);
    }
}

// ---------------------------------------------------------------------------
// K2: 3x3 conv 64 -> 18 (offsets) via bf16 MFMA, XCD swizzle.
// ---------------------------------------------------------------------------
__global__ __launch_bounds__(256,2) void k_offset_mfma(
    const bf16* __restrict__ feats2,
    const unsigned* __restrict__ pwb,   // [tap][cq][hf][oc32][cl4] u32
    const float* __restrict__ pb,
    bf16* __restrict__ offs)
{
    int bid = blockIdx.x;
    int xcd  = bid & 7;
    int h    = (bid >> 3) & 127;
    int pass = bid >> 10;
    int zb   = xcd + 8*pass;

    int t = threadIdx.x;
    int lane = t & 63, w = t >> 6;
    int l31 = lane & 31, half = lane >> 5;

    __shared__ unsigned short xs[3*132*68];   // 53.9 KB

    const unsigned short* fin = (const unsigned short*)(feats2 + (size_t)zb*FSL);
    for (int i=t; i<3120; i+=256){
        int row = i / 1040;
        int r   = i % 1040;
        int col = r >> 3, q = r & 7;
        uint4 v = *(const uint4*)(fin + ((size_t)(h+row)*XW + col)*64 + q*8);
        *(uint4*)&xs[(row*132 + col)*68 + q*8] = v;
    }
    __syncthreads();

    f32x16 acc;
    #pragma unroll
    for (int e=0;e<16;e++) acc[e] = 0.f;

    int pxw = 32*w + l31;
    #pragma unroll
    for (int tap=0; tap<9; tap++){
        int ky = tap/3, kx = tap%3;
        const unsigned short* arow = &xs[(ky*132 + pxw + kx)*68 + half*8];
        const unsigned* brow = pwb + (((size_t)tap*4)*2 + half)*128 + l31*4;
        #pragma unroll
        for (int cq=0; cq<4; cq++){
            s16x8 a  = *(const s16x8*)(arow + cq*16);
            s16x8 b0 = *(const s16x8*)(brow + cq*256);
            acc = __builtin_amdgcn_mfma_f32_32x32x16_bf16(a, b0, acc, 0,0,0);
        }
    }
    __syncthreads();

    unsigned short* ep = (unsigned short*)xs;   // [oc 18][132 pad]
    if (l31 < 18){
        float bias = pb[l31];
        #pragma unroll
        for (int rg=0; rg<4; rg++){
            int m0 = 32*w + 4*half + 8*rg;
            #pragma unroll
            for (int e=0;e<4;e++)
                ep[l31*132 + m0+e] = b16u(acc[4*rg+e] + bias);
        }
    }
    __syncthreads();
    unsigned short* obase = (unsigned short*)(offs + (size_t)zb*18*HW) ;
    for (int i=t; i<288; i+=256){
        int oc = i >> 4, sg = i & 15;
        *(uint4*)(obase + (size_t)oc*HW + h*W + sg*8) = *(const uint4*)(ep + oc*132 + sg*8);
    }
}

// ---------------------------------------------------------------------------
// K3a: deform sampling + dw einsum via bf16 MFMA — channel-major gather
// (R9 structure) + cooperative per-pixel coord compute in LDS (8x dedup).
// grid 2048 1-D, XCD swizzle.
// ---------------------------------------------------------------------------
__global__ __launch_bounds__(256,4) void k_deform_mfma(
    const bf16* __restrict__ feats2,
    const bf16* __restrict__ offs,
    const unsigned* __restrict__ dwb2,  // [n][oc][cp32] u32
    const float* __restrict__ db,
    bf16* __restrict__ dout2)
{
    int bid = blockIdx.x;
    int xcd  = bid & 7;
    int h    = (bid >> 3) & 127;
    int pass = bid >> 10;
    int zb   = xcd + 8*pass;

    int t = threadIdx.x;
    int lane = t & 63, w = t >> 6;
    int l31 = lane & 31, half = lane >> 5;
    int pxg = t >> 3;                 // 0..31, pixel group (gather phase)
    int cq  = t & 7;                  // which 8-ch slice of the 64-ch line
    int sub_w = cq >> 1;              // A-frag sub (0..3)
    int hf8   = cq & 1;               // A-frag half (0..1)

    #define AROW 516                   // u32 row stride (8 rows)
    __shared__ unsigned smem_d[8*AROW + 2304 + 1024];  // A 16.5KB + B 9.2KB + coords 4KB
    unsigned* Asu = smem_d;
    unsigned* Bsu = smem_d + 8*AROW;
    unsigned* Cd  = smem_d + 8*AROW + 2304;   // [px 128][8]: glt,glb,grt,grb,base,dxo,dyo,pad

    const bf16* obase = offs + (size_t)zb*18*HW + h*W;
    const unsigned short* fbase = (const unsigned short*)(feats2 + (size_t)zb*FSL);

    f32x16 acc0, acc1;
    #pragma unroll
    for (int e=0;e<16;e++){ acc0[e]=0.f; acc1[e]=0.f; }

    for (int n=0; n<9; n++){
        // stage B for this n
        const uint4* dsrc = (const uint4*)(dwb2 + n*2048);
        #pragma unroll
        for (int i=0;i<2;i++){
            int j = t + 256*i;
            int idx4 = j*4;
            int oc = idx4 >> 5, cp = idx4 & 31;
            *(uint4*)&Bsu[oc*36 + cp] = dsrc[j];
        }
        // cooperative coords: thread t<128 computes pixel t once (was 8x dup)
        if (t < 128){
            float offy = b2f(obase[n*HW + t]);
            float offx = b2f(obase[(n+9)*HW + t]);
            float py  = (float)(h + n/3) + offy;
            float pxf = (float)(t + n%3) + offx;
            float fy = floorf(py), fx = floorf(pxf);
            float lty = fminf(fmaxf(fy,     0.f),129.f);
            float ltx = fminf(fmaxf(fx,     0.f),129.f);
            float rby = fminf(fmaxf(fy+1.f, 0.f),129.f);
            float rbx = fminf(fmaxf(fx+1.f, 0.f),129.f);
            float pyc = fminf(fmaxf(py,     0.f),129.f);
            float pxc = fminf(fmaxf(pxf,    0.f),129.f);
            float ay = 1.f + (lty-pyc), by = 1.f - (rby-pyc);
            float ax = 1.f + (ltx-pxc), bx = 1.f - (rbx-pxc);
            unsigned* cp = &Cd[t*8];
            cp[0] = __builtin_bit_cast(unsigned, ay*ax);
            cp[1] = __builtin_bit_cast(unsigned, ay*bx);
            cp[2] = __builtin_bit_cast(unsigned, by*ax);
            cp[3] = __builtin_bit_cast(unsigned, by*bx);
            cp[4] = (unsigned)(((int)lty*XW + (int)ltx)*64);
            cp[5] = (unsigned)(((int)rbx - (int)ltx)*64);
            cp[6] = (unsigned)(((int)rby - (int)lty)*XW*64);
        }
        __syncthreads();
        // gather: 4 slots; coords from LDS broadcast (8 lanes share px)
        #pragma unroll
        for (int s=0; s<4; s++){
            int px = s*32 + pxg;
            const unsigned* cp = &Cd[px*8];
            uint4 c0 = *(const uint4*)cp;
            uint4 c1 = *(const uint4*)(cp + 4);
            float glt = __builtin_bit_cast(float, c0.x);
            float glb = __builtin_bit_cast(float, c0.y);
            float grt = __builtin_bit_cast(float, c0.z);
            float grb = __builtin_bit_cast(float, c0.w);
            int base = (int)c1.x;
            int dxo  = (int)c1.y;
            int dyo  = (int)c1.z;

            const unsigned short* fc = fbase + base + cq*8;
            unsigned LT[4], LB[4], RT[4], RB[4];
            *(uint4*)LT = *(const uint4*)(fc);
            *(uint4*)LB = *(const uint4*)(fc+dxo);
            *(uint4*)RT = *(const uint4*)(fc+dyo);
            *(uint4*)RB = *(const uint4*)(fc+dyo+dxo);
            unsigned pk[4];
            #pragma unroll
            for (int jq=0;jq<4;jq++){
                float2 a = up2(LT[jq]), bq = up2(LB[jq]);
                float2 c = up2(RT[jq]), dq = up2(RB[jq]);
                float slo = glt*a.x + glb*bq.x + grt*c.x + grb*dq.x;
                float shi = glt*a.y + glb*bq.y + grt*c.y + grb*dq.y;
                pk[jq] = pack2(slo, shi);
            }
            uint4 av; av.x=pk[0]; av.y=pk[1]; av.z=pk[2]; av.w=pk[3];
            *(uint4*)&Asu[(sub_w*2 + hf8)*AROW + px*4] = av;
        }
        __syncthreads();
        const unsigned short* As16 = (const unsigned short*)Asu;
        const unsigned short* Bs16 = (const unsigned short*)Bsu;
        #pragma unroll
        for (int s=0;s<4;s++){
            s16x8 a  = *(const s16x8*)(As16 + (s*2+half)*(AROW*2) + (32*w + l31)*8);
            s16x8 b0 = *(const s16x8*)(Bs16 + (l31*36 + s*8 + half*4)*2);
            s16x8 b1 = *(const s16x8*)(Bs16 + ((32+l31)*36 + s*8 + half*4)*2);
            acc0 = __builtin_amdgcn_mfma_f32_32x32x16_bf16(a, b0, acc0, 0,0,0);
            acc1 = __builtin_amdgcn_mfma_f32_32x32x16_bf16(a, b1, acc1, 0,0,0);
        }
        __syncthreads();
    }

    // epilogue: +db, ep[px][oc] u16 == dout2 row layout, straight copy out
    unsigned short* ep = (unsigned short*)smem_d;   // overlay (safe: barrier above)
    #pragma unroll
    for (int nt=0; nt<2; nt++){
        int oc = nt*32 + l31;
        float bias = db[oc];
        const f32x16& A = nt ? acc1 : acc0;
        #pragma unroll
        for (int rg=0; rg<4; rg++){
            int m0 = 32*w + 4*half + 8*rg;
            #pragma unroll
            for (int e=0;e<4;e++)
                ep[(m0+e)*64 + oc] = b16u(A[4*rg+e] + bias);
        }
    }
    __syncthreads();
    uint4* dst = (uint4*)((unsigned short*)dout2 + ((size_t)zb*128 + h)*(128*64));
    #pragma unroll
    for (int i=0;i<4;i++)
        dst[t + 256*i] = ((const uint4*)ep)[t + 256*i];
    #undef AROW
}

// ---------------------------------------------------------------------------
// K3b: 1x1 conv 256 -> 64 + cb + ReLU via bf16 MFMA. grid (128 h, 4 b).
// ---------------------------------------------------------------------------
__global__ __launch_bounds__(256,2) void k_combine_mfma(
    const bf16* __restrict__ dout2,
    const unsigned* __restrict__ cwb2,  // [oc][cp128] u32
    const float* __restrict__ cb,
    float* __restrict__ out)
{
    int h = blockIdx.x, b = blockIdx.y;
    int t = threadIdx.x;
    int px = t & 127, hf = t >> 7;
    int lane = t & 63, w = t >> 6, l31 = lane & 31, half = lane >> 5;

    __shared__ unsigned Bsu[64*132];
    __shared__ unsigned Asu2[1024];

    for (int i=t; i<8192; i+=256){
        int oc = i>>7, cp = i&127;
        Bsu[oc*132 + cp] = cwb2[i];
    }
    f32x16 acc0, acc1;
    #pragma unroll
    for (int e=0;e<16;e++){ acc0[e]=0.f; acc1[e]=0.f; }

    const unsigned short* dbase0 = (const unsigned short*)dout2;
    size_t rowsel = ((size_t)b*128 + h)*128 + px;
    uint4 v = *(const uint4*)(dbase0 + rowsel*64 + hf*8);
    for (int kc=0; kc<16; kc++){
        *(uint4*)&Asu2[(hf*128+px)*4] = v;
        __syncthreads();
        if (kc < 15){
            int kn = kc+1;
            int d = kn>>2, c16 = kn&3;
            v = *(const uint4*)(dbase0 + ((size_t)d*4*128*128*64 + rowsel*64) + c16*16 + hf*8);
        }
        const unsigned short* As16 = (const unsigned short*)Asu2;
        const unsigned short* Bs16 = (const unsigned short*)Bsu;
        s16x8 a  = *(const s16x8*)(As16 + (half*128 + 32*w + l31)*8);
        s16x8 b0 = *(const s16x8*)(Bs16 + (l31*132 + kc*8 + half*4)*2);
        s16x8 b1 = *(const s16x8*)(Bs16 + ((32+l31)*132 + kc*8 + half*4)*2);
        acc0 = __builtin_amdgcn_mfma_f32_32x32x16_bf16(a, b0, acc0, 0,0,0);
        acc1 = __builtin_amdgcn_mfma_f32_32x32x16_bf16(a, b1, acc1, 0,0,0);
        __syncthreads();
    }
    float* ep = (float*)Bsu;
    #pragma unroll
    for (int nt=0; nt<2; nt++){
        int oc = nt*32 + l31;
        float bias = cb[oc];
        const f32x16& A = nt ? acc1 : acc0;
        #pragma unroll
        for (int rg=0; rg<4; rg++){
            int m0 = 32*w + 4*half + 8*rg;
            #pragma unroll
            for (int e=0;e<4;e++)
                ep[oc*132 + m0+e] = fmaxf(A[4*rg+e] + bias, 0.f);
        }
    }
    __syncthreads();
    for (int i=t; i<2048; i+=256){
        int oc = i>>5, sg = i&31;
        *(uint4*)&out[(((size_t)b*64+oc)*128 + h)*128 + sg*4] = *(const uint4*)&ep[oc*132 + sg*4];
    }
}

extern "C" void kernel_launch(void* const* d_in, const int* in_sizes, int n_in,
                              void* d_out, int out_size, void* d_ws, size_t ws_size,
                              hipStream_t stream) {
    const float* x  = (const float*)d_in[0];
    const float* w1 = (const float*)d_in[1];
    const float* b1 = (const float*)d_in[2];
    const float* w2 = (const float*)d_in[3];
    const float* b2 = (const float*)d_in[4];
    const float* w3 = (const float*)d_in[5];
    const float* b3 = (const float*)d_in[6];
    const float* w4 = (const float*)d_in[7];
    const float* b4 = (const float*)d_in[8];
    const float* pw = (const float*)d_in[9];
    const float* pb = (const float*)d_in[10];
    const float* dw = (const float*)d_in[11];
    const float* db = (const float*)d_in[12];
    const float* cw = (const float*)d_in[13];
    const float* cb = (const float*)d_in[14];
    float* out = (float*)d_out;

    bf16* feats2 = (bf16*)d_ws;                             // 34.6 MB
    bf16* offs   = feats2 + (size_t)16*FSL;                 // 9.4 MB
    bf16* region2 = offs + (size_t)16*18*HW;
    bf16* dout2  = region2;                                 // 33.55 MB
    unsigned* xt  = (unsigned*)region2;                     // 21.2 MB (dead before dout2)
    unsigned* wbt = xt + (size_t)4*8*XTD*XTD*8;             // 0.59 MB (dead before dout2)
    unsigned* dwb2 = (unsigned*)(dout2 + (size_t)16*128*128*64);  // 73.7 KB
    unsigned* cwb2 = dwb2 + 18432;                          // 32.8 KB
    unsigned* pwb  = cwb2 + 8192;                           // 36.9 KB

    k_prep        <<<dim3(1740),    256, 0, stream>>>(w1,w2,w3,w4, dw, cw, pw,
                                                      (uint4*)xt, wbt, dwb2, cwb2, pwb);
    k_xprep       <<<dim3(128,4),   256, 0, stream>>>(x, xt);
    k_branch_mfma <<<dim3(1024),    256, 0, stream>>>(xt, wbt, b1,b2,b3,b4, feats2);
    k_offset_mfma <<<dim3(2048),    256, 0, stream>>>(feats2, pwb, pb, offs);
    k_deform_mfma <<<dim3(2048),    256, 0, stream>>>(feats2, offs, dwb2, db, dout2);
    k_combine_mfma<<<dim3(128,4),   256, 0, stream>>>(dout2, cwb2, cb, out);
}